// Round 2
// baseline (42.209 us; speedup 1.0000x reference)
//
#include <hip/hip_runtime.h>

typedef float f4 __attribute__((ext_vector_type(4)));

// Routing: out[row] = x[row] if expert 0 is in top-2 of x[row][0..7] else 0.
// top_k tie-break favors lower index => expert 0 in top-2 iff
// count(x[j] > x[0], j=1..7) <= 1.
//
// Lane-pair cooperative layout: lane i loads contiguous float4 #i.
// Even lane of a pair holds experts 0-3, odd lane experts 4-7 of one row.
__global__ void __launch_bounds__(256) route_e0_kernel(
    const f4* __restrict__ x, f4* __restrict__ out, int nvec) {
    int idx = blockIdx.x * blockDim.x + threadIdx.x;
    int stride = gridDim.x * blockDim.x;
    int lane = threadIdx.x & 63;
    int src = lane & ~1;  // even lane of my pair

    for (int v = idx; v < nvec; v += stride) {
        f4 a = x[v];  // fully contiguous: 16 B/lane, 1 KiB/wave/instr
        float x0 = __shfl(a.x, src, 64);
        // even lane: a.x == x0, so (a.x > x0) contributes 0 — branch-free
        int c = (a.x > x0) + (a.y > x0) + (a.z > x0) + (a.w > x0);
        c += __shfl_xor(c, 1, 64);
        if (c > 1) a = (f4)(0.0f);
        // nt store: keep the write stream from evicting the L3-resident input
        __builtin_nontemporal_store(a, &out[v]);
    }
}

extern "C" void kernel_launch(void* const* d_in, const int* in_sizes, int n_in,
                              void* d_out, int out_size, void* d_ws, size_t ws_size,
                              hipStream_t stream) {
    const f4* x = (const f4*)d_in[0];
    f4* out = (f4*)d_out;
    int nvec = in_sizes[0] / 4;  // float4 count (2 per row)

    const int block = 256;
    int grid = (nvec + block - 1) / block;
    if (grid > 2048) grid = 2048;  // grid-stride the rest (memory-bound)
    route_e0_kernel<<<grid, block, 0, stream>>>(x, out, nvec);
}

// Round 3
// 40.938 us; speedup vs baseline: 1.0311x; 1.0311x over previous
//
#include <hip/hip_runtime.h>

// Routing: out[row] = x[row] if expert 0 is in top-2 of x[row][0..7] else 0.
// top_k tie-break favors lower index => expert 0 in top-2 iff
// count(x[j] > x[0], j=1..7) <= 1.
//
// R2 post-mortem: nt-stores regressed (forfeit L3 write absorption, -2%);
// stride-2 float4 loads coalesce fine at the cache-line level. This is the
// proven R1 configuration: 41.3 us ~= 256 MiB @ 6.5 TB/s effective, at the
// measured mixed-copy HBM ceiling (6.29 TB/s).
__global__ void __launch_bounds__(256) route_e0_kernel(
    const float4* __restrict__ x, float4* __restrict__ out, int nrows) {
    int idx = blockIdx.x * blockDim.x + threadIdx.x;
    int stride = gridDim.x * blockDim.x;
    for (int r = idx; r < nrows; r += stride) {
        float4 a = x[2 * r];       // experts 0..3
        float4 b = x[2 * r + 1];   // experts 4..7
        float x0 = a.x;
        int cnt = (a.y > x0) + (a.z > x0) + (a.w > x0)
                + (b.x > x0) + (b.y > x0) + (b.z > x0) + (b.w > x0);
        if (cnt > 1) {
            a = make_float4(0.f, 0.f, 0.f, 0.f);
            b = make_float4(0.f, 0.f, 0.f, 0.f);
        }
        out[2 * r]     = a;
        out[2 * r + 1] = b;
    }
}

extern "C" void kernel_launch(void* const* d_in, const int* in_sizes, int n_in,
                              void* d_out, int out_size, void* d_ws, size_t ws_size,
                              hipStream_t stream) {
    const float4* x = (const float4*)d_in[0];
    float4* out = (float4*)d_out;
    int nrows = in_sizes[0] / 8;  // 8 experts per row

    const int block = 256;
    int grid = (nrows + block - 1) / block;
    if (grid > 2048) grid = 2048;  // grid-stride the rest (memory-bound)
    route_e0_kernel<<<grid, block, 0, stream>>>(x, out, nrows);
}